// Round 4
// baseline (1365.606 us; speedup 1.0000x reference)
//
#include <hip/hip_runtime.h>
#include <math.h>

#define FHh 480
#define FWw 640
#define NPIX (FHh*FWw)          // 307200
#define NSEMC 16
#define COBS 20
#define MAPC 480
#define VRc 100
#define HZc 80
#define MINZc 13
#define MAXZc 25
#define ZW 12
#define ZWP 13                  // padded z stride for LDS bank spread
#define NB 4
#define NBINS_DIM 101
#define NBINS_ROW 101
#define COUNTS_PAD 40960        // 1024*40 >= 40804
#define BANDMAX 600000          // est. band points ~283K; 2.1x margin
#define NTOT (NB*NPIX)          // 1,228,800

// ---------------- pose + affine params ----------------
__global__ void pose_kernel(const float* __restrict__ pose_obs,
                            const float* __restrict__ poses_last,
                            float* __restrict__ out_p1,
                            float* __restrict__ out_p2,
                            float* __restrict__ params)
{
    int b = threadIdx.x;
    if (b >= NB) return;
    float pl0 = poses_last[b*3+0], pl1 = poses_last[b*3+1], pl2 = poses_last[b*3+2];
    float po0 = pose_obs[b*3+0],  po1 = pose_obs[b*3+1],  po2 = pose_obs[b*3+2];
    const float DEGf = 57.29577951308232f;
    float t0 = pl2 / DEGf;
    float s = sinf(t0), c = cosf(t0);
    float y_new = pl1 + po0*s + po1*c;
    float x_new = pl0 + po0*c - po1*s;
    float t_new = pl2 + po2*DEGf;
    t_new = fmodf(t_new - 180.0f, 360.0f) + 180.0f;
    t_new = fmodf(t_new + 180.0f, 360.0f) - 180.0f;
    out_p1[b*3+0]=x_new; out_p1[b*3+1]=y_new; out_p1[b*3+2]=t_new;
    out_p2[b*3+0]=x_new; out_p2[b*3+1]=y_new; out_p2[b*3+2]=t_new;
    float sx = -(((x_new*100.0f)/5.0f - 240.0f)/240.0f);
    float sy = -(((y_new*100.0f)/5.0f - 240.0f)/240.0f);
    float st_t = (90.0f - t_new) * 0.017453292519943295f;
    params[b*4+0] = cosf(st_t);
    params[b*4+1] = sinf(st_t);
    params[b*4+2] = sx;
    params[b*4+3] = sy;
}

// ---------------- per-pixel projection math ----------------
__device__ __forceinline__ float4 pixel_pos(const float* __restrict__ obsb,
                                            const float* __restrict__ sh,
                                            int b, int n, float fconst)
{
    int col = n % FWw, row = n / FWw;
    float depth = obsb[3*NPIX + n];
    const float4 s4 = ((const float4*)sh)[(size_t)b*NPIX + n];
    float sm = (((s4.x + s4.y) + s4.z) + s4.w) / 4.0f;
    float factor = 1.0f + sm;

    float X = ((float)col - 319.5f) * depth / fconst;
    float Z = ((float)(FHh-1-row) - 239.5f) * depth / fconst;
    float x_s = X + 250.0f;
    float z_s = Z + 88.0f;
    float xn = (x_s/5.0f - 50.0f)/100.0f*2.0f;
    float yn = (depth/5.0f - 50.0f)/100.0f*2.0f;
    float zn = (z_s/5.0f - 32.0f)/80.0f*2.0f;
    xn = fminf(fmaxf(xn,-1.0f),1.0f);
    yn = fminf(fmaxf(yn,-1.0f),1.0f);
    zn = fminf(fmaxf(zn,-1.0f),1.0f);
    float pos0 = (xn*100.0f)/2.0f + 50.0f;
    float pos1 = (yn*100.0f)/2.0f + 50.0f;
    float pos2 = (zn*80.0f)/2.0f + 40.0f;
    return make_float4(pos0, pos1, pos2, factor);
}

// A dim contributes iff some tap p with weight>0 lies in (0, GD).
__device__ __forceinline__ bool dim_ok(float p, int GD)
{
    int f = (int)floorf(p);
    float fr = p - (float)f;
    bool t0 = (f > 0) && (f < GD);
    bool t1 = (f + 1 < GD) && (fr > 0.0f);
    return t0 || t1;
}

// ---------------- pass A: occupancy scatter (global atomics) + band count ----
__global__ __launch_bounds__(256)
void project_kernel(const float* __restrict__ obs,
                    const float* __restrict__ sh,
                    float* __restrict__ occ,
                    int* __restrict__ countsB,
                    float fconst)
{
    int g = blockIdx.x*blockDim.x + threadIdx.x;
    if (g >= NTOT) return;
    int b = g / NPIX, n = g % NPIX;
    const float* obsb = obs + (size_t)b*COBS*NPIX;
    float4 P = pixel_pos(obsb, sh, b, n, fconst);

    int f0 = (int)floorf(P.x);
    int f1 = (int)floorf(P.y);
    int f2 = (int)floorf(P.z);
    float* occb = occ + (size_t)b*VRc*VRc*HZc;

    #pragma unroll
    for (int dj = 0; dj < 2; ++dj) {
        int tj = f1 + dj;
        if (tj < 1 || tj > 99) continue;
        float wy = 1.0f - fabsf(P.y - (float)tj);
        if (wy <= 0.0f) continue;
        #pragma unroll
        for (int di = 0; di < 2; ++di) {
            int ti = f0 + di;
            if (ti < 1 || ti > 99) continue;
            float wx = 1.0f - fabsf(P.x - (float)ti);
            if (wx <= 0.0f) continue;
            float wxy = wx * wy;
            #pragma unroll
            for (int dz = 0; dz < 2; ++dz) {
                int q = f2 + dz;
                if (q < 1 || q > 79) continue;
                float w = wxy * (1.0f - fabsf(P.z - (float)q));
                if (w > 0.0f)
                    atomicAdd(&occb[((size_t)tj*VRc + ti)*HZc + q], P.w * w);
            }
        }
    }

    // band predicate (must be identical in band_scatter_kernel)
    if (dim_ok(P.x, VRc) && dim_ok(P.y, VRc) && P.z > 12.0f && P.z < 25.0f) {
        int bid = (b*NBINS_DIM + f1)*NBINS_ROW + f0;   // f1-major sort!
        atomicAdd(&countsB[bid], 1);
    }
}

// ---------------- exclusive scan (+working copy) ----------------
// layout at base: [countsB | offsetsWork], each COUNTS_PAD ints
__global__ void scan_kernel(int* __restrict__ base)
{
    int* cnt = base;
    int* wrk = cnt + COUNTS_PAD;
    __shared__ int part[1024];
    int t = threadIdx.x;
    const int CHUNK = COUNTS_PAD / 1024;   // 40
    int bo = t*CHUNK;
    int s = 0;
    for (int k = 0; k < CHUNK; ++k) s += cnt[bo+k];
    part[t] = s;
    __syncthreads();
    for (int off = 1; off < 1024; off <<= 1) {
        int v = (t >= off) ? part[t-off] : 0;
        __syncthreads();
        part[t] += v;
        __syncthreads();
    }
    int run = part[t] - s;
    for (int k = 0; k < CHUNK; ++k) {
        int c = cnt[bo+k];
        cnt[bo+k] = run;
        wrk[bo+k] = run;
        run += c;
    }
}

// ---------------- pass B: band-only counting-sort + semantic packing --------
__global__ __launch_bounds__(256)
void band_scatter_kernel(const float* __restrict__ obs,
                         const float* __restrict__ sh,
                         int* __restrict__ offsetsWork,
                         float4* __restrict__ bandPos,
                         float4* __restrict__ bandSem,
                         float fconst)
{
    int g = blockIdx.x*blockDim.x + threadIdx.x;
    if (g >= NTOT) return;
    int b = g / NPIX, n = g % NPIX;
    const float* obsb = obs + (size_t)b*COBS*NPIX;
    float4 P = pixel_pos(obsb, sh, b, n, fconst);

    if (!(dim_ok(P.x, VRc) && dim_ok(P.y, VRc) && P.z > 12.0f && P.z < 25.0f))
        return;
    int f0 = (int)floorf(P.x);
    int f1 = (int)floorf(P.y);
    int bid = (b*NBINS_DIM + f1)*NBINS_ROW + f0;
    int dst = atomicAdd(&offsetsWork[bid], 1);
    if (dst >= BANDMAX) return;
    bandPos[dst] = P;
    float4* bs = bandSem + (size_t)dst*4;
    #pragma unroll
    for (int q = 0; q < 4; ++q) {
        float4 e;
        e.x = obsb[(4 + 4*q + 0)*NPIX + n] * P.w;
        e.y = obsb[(4 + 4*q + 1)*NPIX + n] * P.w;
        e.z = obsb[(4 + 4*q + 2)*NPIX + n] * P.w;
        e.w = obsb[(4 + 4*q + 3)*NPIX + n] * P.w;
        bs[q] = e;
    }
}

// ---------------- pass C: per-row gather. 800 blocks, all co-resident. -----
// Block = (j-row, i-half, b): 50 cells. Band stream read as 2 contiguous
// segments (f1 in {j-1, j}); 16 lanes per point, lane c owns channel c.
// Occupancy read contiguously from the voxel grid and reduced.
__global__ __launch_bounds__(256)
void gather_rows_kernel(const float* __restrict__ occ,
                        const float4* __restrict__ bandPos,
                        const float* __restrict__ bandSemF,
                        const int* __restrict__ offsetsB,
                        float* __restrict__ avwin,
                        float* __restrict__ fp_out)
{
    int j  = blockIdx.x >> 1;
    int i0 = (blockIdx.x & 1) * 50;
    int b  = blockIdx.y;
    int tid = threadIdx.x;

    __shared__ float accSem[50*NSEMC*ZWP];   // 10400 floats (41.6 KB)
    __shared__ float occL[50*81];            // 4050 floats (16.2 KB), pad 81

    for (int k = tid; k < 50*NSEMC*ZWP; k += 256) accSem[k] = 0.0f;
    __syncthreads();

    if (j >= 1) {
        int f0lo = (i0 == 0) ? 0 : (i0 - 1);
        int f0hi = i0 + 49;                    // <= 99
        int tmin = (i0 == 0) ? 1 : i0;
        int cgrp = tid & 15;
        #pragma unroll
        for (int seg = 0; seg < 2; ++seg) {
            int f1r = j - 1 + seg;
            int rbB = (b*NBINS_DIM + f1r)*NBINS_ROW;
            int s = offsetsB[rbB + f0lo];
            int e = offsetsB[rbB + f0hi + 1];
            if (s < 0) s = 0;
            if (e > BANDMAX) e = BANDMAX;      // OOB hardening
            for (int idx = s + (tid >> 4); idx < e; idx += 16) {
                float4 P = bandPos[idx];
                float wy = 1.0f - fabsf(P.y - (float)j);
                if (wy <= 0.0f) continue;
                float ev = bandSemF[(size_t)idx*16 + cgrp];
                int f0c = (int)floorf(P.x);
                int qA  = (int)floorf(P.z);
                #pragma unroll
                for (int di = 0; di < 2; ++di) {
                    int ti = f0c + di;
                    if (ti < tmin || ti > i0 + 49) continue;
                    float wx = 1.0f - fabsf(P.x - (float)ti);
                    if (wx <= 0.0f) continue;
                    float wxy = wx * wy;
                    int base = ((ti - i0)*NSEMC + cgrp)*ZWP - MINZc;
                    #pragma unroll
                    for (int dz = 0; dz < 2; ++dz) {
                        int q = qA + dz;
                        if (q < MINZc || q >= MAXZc) continue;
                        float w = wxy * (1.0f - fabsf(P.z - (float)q));
                        if (w > 0.0f) atomicAdd(&accSem[base + q], ev * w);
                    }
                }
            }
        }
    }

    // stage this row's occupancy (fully contiguous in global memory)
    const float* orow = occ + (((size_t)b*VRc + j)*VRc + i0)*HZc;
    for (int k = tid; k < 50*HZc; k += 256)
        occL[(k/HZc)*81 + (k%HZc)] = orow[k];
    __syncthreads();

    float* avb = avwin + (size_t)b*18*10000;
    int cell0 = j*100 + i0;

    for (int c = tid; c < 50; c += 256) {
        float agent = 0.0f, all = 0.0f;
        for (int z = 0; z < HZc; ++z) {
            float r = rintf(occL[c*81 + z]);
            all += r;
            if (z >= MINZc && z < MAXZc) agent += r;
        }
        float va = fminf(fmaxf(agent, 0.0f), 1.0f);
        avb[cell0 + c] = va;
        fp_out[(size_t)b*10000 + cell0 + c] = va;
        avb[10000 + cell0 + c] = fminf(fmaxf(all, 0.0f), 1.0f);
    }
    for (int t = tid; t < 50*NSEMC; t += 256) {
        int c = t >> 4, ch = t & 15;
        float s = 0.0f;
        #pragma unroll
        for (int z = 0; z < ZW; ++z) s += rintf(accSem[(c*NSEMC + ch)*ZWP + z]);
        avb[(2+ch)*10000 + cell0 + c] = fminf(fmaxf(s*0.2f, 0.0f), 1.0f);
    }
}

// ---------------- fused double grid_sample + max ----------------
__device__ __forceinline__ float grid1d(int i) {
    return (float)(-1.0 + (double)i * (2.0/479.0));
}

__global__ void map_kernel(const float* __restrict__ maps_last,
                           const float* __restrict__ avwin,
                           const float* __restrict__ params,
                           float* __restrict__ map_out)
{
    int t = blockIdx.x*blockDim.x + threadIdx.x;
    if (t >= NB*MAPC*MAPC) return;
    int w = t % MAPC;
    int h = (t / MAPC) % MAPC;
    int b = t / (MAPC*MAPC);
    float ct = params[b*4+0], st = params[b*4+1];
    float sx = params[b*4+2], sy = params[b*4+3];

    float xg = grid1d(w) + sx;
    float yg = grid1d(h) + sy;
    float xt = ((xg + 1.0f)*479.0f)/2.0f;
    float yt = ((yg + 1.0f)*479.0f)/2.0f;
    float xf = floorf(xt), yf = floorf(yt);

    float acc[18];
    #pragma unroll
    for (int k=0;k<18;k++) acc[k]=0.0f;
    const float* avb = avwin + (size_t)b*18*10000;

    #pragma unroll
    for (int oy=0; oy<2; ++oy) {
        #pragma unroll
        for (int ox=0; ox<2; ++ox) {
            float qx = xf + (float)ox, qy = yf + (float)oy;
            if (!(qx >= 0.0f && qx < 480.0f && qy >= 0.0f && qy < 480.0f)) continue;
            float wo = (ox ? (xt - xf) : (xf + 1.0f - xt))
                     * (oy ? (yt - yf) : (yf + 1.0f - yt));
            int oxi = (int)qx, oyi = (int)qy;
            float gxr = grid1d(oxi), gyr = grid1d(oyi);
            float xr = ct*gxr - st*gyr;
            float yr = st*gxr + ct*gyr;
            float xp = ((xr + 1.0f)*479.0f)/2.0f;
            float yp = ((yr + 1.0f)*479.0f)/2.0f;
            float xpf = floorf(xp), ypf = floorf(yp);
            float R[18];
            #pragma unroll
            for (int k=0;k<18;k++) R[k]=0.0f;
            #pragma unroll
            for (int iy=0; iy<2; ++iy) {
                #pragma unroll
                for (int ix=0; ix<2; ++ix) {
                    float rx = xpf + (float)ix, ry = ypf + (float)iy;
                    if (!(rx >= 0.0f && rx < 480.0f && ry >= 0.0f && ry < 480.0f)) continue;
                    int rxi = (int)rx, ryi = (int)ry;
                    if (ryi < 240 || ryi >= 340 || rxi < 190 || rxi >= 290) continue;
                    float wi = (ix ? (xp - xpf) : (xpf + 1.0f - xp))
                             * (iy ? (yp - ypf) : (ypf + 1.0f - yp));
                    const float* p = avb + (ryi-240)*VRc + (rxi-190);
                    #pragma unroll
                    for (int k=0;k<18;k++) R[k] += wi * p[k*10000];
                }
            }
            #pragma unroll
            for (int k=0;k<18;k++) acc[k] += wo * R[k];
        }
    }

    #pragma unroll
    for (int c=0;c<COBS;c++) {
        size_t o = (((size_t)b*COBS + c)*MAPC + h)*MAPC + w;
        float tv = (c==0) ? acc[0] : (c==1) ? acc[1] : (c>=4) ? acc[c-2] : 0.0f;
        map_out[o] = fmaxf(maps_last[o], tv);
    }
}

extern "C" void kernel_launch(void* const* d_in, const int* in_sizes, int n_in,
                              void* d_out, int out_size, void* d_ws, size_t ws_size,
                              hipStream_t stream)
{
    const float* obs        = (const float*)d_in[0];
    const float* pose_obs   = (const float*)d_in[1];
    const float* maps_last  = (const float*)d_in[2];
    const float* poses_last = (const float*)d_in[3];
    const float* sh         = (const float*)d_in[4];
    float* out = (float*)d_out;

    float* fp_out  = out;                       // 40,000
    float* map_out = out + 40000;               // 18,432,000
    float* poses1  = out + 40000 + 18432000;    // 12
    float* poses2  = poses1 + 12;               // 12

    float* params = (float*)d_ws;               // 16 floats
    float* avwin  = params + 16;                // 720,000 floats

    // Scratch inside map_out region (fully overwritten by final map_kernel):
    //  occ        : NB*100*100*80 = 3,200,000 floats
    //  countsB    : 40,960 ints
    //  offsetsWork: 40,960 ints
    //  bandPos    : BANDMAX*4  = 2,400,000 floats
    //  bandSem    : BANDMAX*16 = 9,600,000 floats
    //  total = 15,281,920 floats <= 18,432,000
    float* occ          = map_out;
    int*   countsB      = (int*)(map_out + 3200000);
    int*   offsetsWork  = countsB + COUNTS_PAD;
    float4* bandPos     = (float4*)(map_out + 3200000 + 2*COUNTS_PAD);
    float4* bandSem     = (float4*)(map_out + 3200000 + 2*COUNTS_PAD + (size_t)BANDMAX*4);

    double rad = 39.5 * 0.017453292519943295;
    float fconst = (float)(320.0 / tan(rad));

    hipLaunchKernelGGL(pose_kernel, dim3(1), dim3(64), 0, stream,
                       pose_obs, poses_last, poses1, poses2, params);

    // zero occ grid + both count arrays in one contiguous memset
    hipMemsetAsync(occ, 0, (size_t)(3200000 + 2*COUNTS_PAD)*sizeof(float), stream);

    hipLaunchKernelGGL(project_kernel, dim3((NTOT+255)/256), dim3(256), 0, stream,
                       obs, sh, occ, countsB, fconst);

    hipLaunchKernelGGL(scan_kernel, dim3(1), dim3(1024), 0, stream, countsB);

    hipLaunchKernelGGL(band_scatter_kernel, dim3((NTOT+255)/256), dim3(256), 0, stream,
                       obs, sh, offsetsWork, bandPos, bandSem, fconst);

    hipLaunchKernelGGL(gather_rows_kernel, dim3(200, NB), dim3(256), 0, stream,
                       occ, bandPos, (const float*)bandSem, countsB, avwin, fp_out);

    hipLaunchKernelGGL(map_kernel, dim3((NB*MAPC*MAPC+255)/256), dim3(256), 0, stream,
                       maps_last, avwin, params, map_out);
}

// Round 5
// 907.361 us; speedup vs baseline: 1.5050x; 1.5050x over previous
//
#include <hip/hip_runtime.h>
#include <math.h>

#define FHh 480
#define FWw 640
#define NPIX (FHh*FWw)          // 307200
#define NSEMC 16
#define COBS 20
#define MAPC 480
#define VRc 100
#define HZc 80
#define MINZc 13
#define MAXZc 25
#define ZW 12
#define ZWP 13                  // padded z stride for LDS bank spread
#define OCCP 81                 // padded z stride for occ LDS
#define NB 4
#define NBINS_DIM 101
#define NBINS_ROW 101
#define COUNTS_PAD 40960        // 1024*40 >= 40804
#define BANDMAX 600000          // est. band points ~283K; 2.1x margin
#define NTOT (NB*NPIX)          // 1,228,800

// ---------------- pose + affine params ----------------
__global__ void pose_kernel(const float* __restrict__ pose_obs,
                            const float* __restrict__ poses_last,
                            float* __restrict__ out_p1,
                            float* __restrict__ out_p2,
                            float* __restrict__ params)
{
    int b = threadIdx.x;
    if (b >= NB) return;
    float pl0 = poses_last[b*3+0], pl1 = poses_last[b*3+1], pl2 = poses_last[b*3+2];
    float po0 = pose_obs[b*3+0],  po1 = pose_obs[b*3+1],  po2 = pose_obs[b*3+2];
    const float DEGf = 57.29577951308232f;
    float t0 = pl2 / DEGf;
    float s = sinf(t0), c = cosf(t0);
    float y_new = pl1 + po0*s + po1*c;
    float x_new = pl0 + po0*c - po1*s;
    float t_new = pl2 + po2*DEGf;
    t_new = fmodf(t_new - 180.0f, 360.0f) + 180.0f;
    t_new = fmodf(t_new + 180.0f, 360.0f) - 180.0f;
    out_p1[b*3+0]=x_new; out_p1[b*3+1]=y_new; out_p1[b*3+2]=t_new;
    out_p2[b*3+0]=x_new; out_p2[b*3+1]=y_new; out_p2[b*3+2]=t_new;
    float sx = -(((x_new*100.0f)/5.0f - 240.0f)/240.0f);
    float sy = -(((y_new*100.0f)/5.0f - 240.0f)/240.0f);
    float st_t = (90.0f - t_new) * 0.017453292519943295f;
    params[b*4+0] = cosf(st_t);
    params[b*4+1] = sinf(st_t);
    params[b*4+2] = sx;
    params[b*4+3] = sy;
}

// ---------------- per-pixel projection math ----------------
__device__ __forceinline__ float4 pixel_pos(const float* __restrict__ obsb,
                                            const float* __restrict__ sh,
                                            int b, int n, float fconst)
{
    int col = n % FWw, row = n / FWw;
    float depth = obsb[3*NPIX + n];
    const float4 s4 = ((const float4*)sh)[(size_t)b*NPIX + n];
    float sm = (((s4.x + s4.y) + s4.z) + s4.w) / 4.0f;
    float factor = 1.0f + sm;

    float X = ((float)col - 319.5f) * depth / fconst;
    float Z = ((float)(FHh-1-row) - 239.5f) * depth / fconst;
    float x_s = X + 250.0f;
    float z_s = Z + 88.0f;
    float xn = (x_s/5.0f - 50.0f)/100.0f*2.0f;
    float yn = (depth/5.0f - 50.0f)/100.0f*2.0f;
    float zn = (z_s/5.0f - 32.0f)/80.0f*2.0f;
    xn = fminf(fmaxf(xn,-1.0f),1.0f);
    yn = fminf(fmaxf(yn,-1.0f),1.0f);
    zn = fminf(fmaxf(zn,-1.0f),1.0f);
    float pos0 = (xn*100.0f)/2.0f + 50.0f;
    float pos1 = (yn*100.0f)/2.0f + 50.0f;
    float pos2 = (zn*80.0f)/2.0f + 40.0f;
    return make_float4(pos0, pos1, pos2, factor);
}

// A dim contributes iff some tap p with weight>0 lies in (0, GD).
__device__ __forceinline__ bool dim_ok(float p, int GD)
{
    int f = (int)floorf(p);
    float fr = p - (float)f;
    bool t0 = (f > 0) && (f < GD);
    bool t1 = (f + 1 < GD) && (fr > 0.0f);
    return t0 || t1;
}

// ---------------- pass A: bin counting only (no atomic storm) ----------------
__global__ __launch_bounds__(256)
void count_kernel(const float* __restrict__ obs,
                  const float* __restrict__ sh,
                  int* __restrict__ counts,
                  int* __restrict__ countsB,
                  float fconst)
{
    int g = blockIdx.x*blockDim.x + threadIdx.x;
    if (g >= NTOT) return;
    int b = g / NPIX, n = g % NPIX;
    const float* obsb = obs + (size_t)b*COBS*NPIX;
    float4 P = pixel_pos(obsb, sh, b, n, fconst);

    if (!(dim_ok(P.x, VRc) && dim_ok(P.y, VRc) && dim_ok(P.z, HZc))) return;
    int f0 = (int)floorf(P.x);   // [0,99]
    int f1 = (int)floorf(P.y);   // [0,99]
    int bid = (b*NBINS_DIM + f1)*NBINS_ROW + f0;   // f1-major
    atomicAdd(&counts[bid], 1);
    if (P.z > 12.0f && P.z < 25.0f) atomicAdd(&countsB[bid], 1);
}

// ---------------- exclusive scan (+working copy) ----------------
// layout at base: [counts | offsetsWork | countsB | offsetsWorkB], each COUNTS_PAD
__global__ void scan_kernel(int* __restrict__ base)
{
    int* cnt = base + (size_t)blockIdx.x * 2 * COUNTS_PAD;
    int* wrk = cnt + COUNTS_PAD;
    __shared__ int part[1024];
    int t = threadIdx.x;
    const int CHUNK = COUNTS_PAD / 1024;   // 40
    int bo = t*CHUNK;
    int s = 0;
    for (int k = 0; k < CHUNK; ++k) s += cnt[bo+k];
    part[t] = s;
    __syncthreads();
    for (int off = 1; off < 1024; off <<= 1) {
        int v = (t >= off) ? part[t-off] : 0;
        __syncthreads();
        part[t] += v;
        __syncthreads();
    }
    int run = part[t] - s;
    for (int k = 0; k < CHUNK; ++k) {
        int c = cnt[bo+k];
        cnt[bo+k] = run;
        wrk[bo+k] = run;
        run += c;
    }
}

// ---------------- pass B: counting-sort scatter + band semantic packing -----
__global__ __launch_bounds__(256)
void scatter_kernel(const float* __restrict__ obs,
                    const float* __restrict__ sh,
                    int* __restrict__ offsetsWork,
                    int* __restrict__ offsetsWorkB,
                    float4* __restrict__ payloadPos,
                    float4* __restrict__ bandPos,
                    float4* __restrict__ bandSem,
                    float fconst)
{
    int g = blockIdx.x*blockDim.x + threadIdx.x;
    if (g >= NTOT) return;
    int b = g / NPIX, n = g % NPIX;
    const float* obsb = obs + (size_t)b*COBS*NPIX;
    float4 P = pixel_pos(obsb, sh, b, n, fconst);

    if (!(dim_ok(P.x, VRc) && dim_ok(P.y, VRc) && dim_ok(P.z, HZc))) return;
    int f0 = (int)floorf(P.x);
    int f1 = (int)floorf(P.y);
    int bid = (b*NBINS_DIM + f1)*NBINS_ROW + f0;

    int dst = atomicAdd(&offsetsWork[bid], 1);
    if (dst < NTOT) payloadPos[dst] = P;

    if (P.z > 12.0f && P.z < 25.0f) {
        int dstB = atomicAdd(&offsetsWorkB[bid], 1);
        if (dstB < BANDMAX) {
            bandPos[dstB] = P;
            float4* bs = bandSem + (size_t)dstB*4;
            #pragma unroll
            for (int q = 0; q < 4; ++q) {
                float4 e;
                e.x = obsb[(4 + 4*q + 0)*NPIX + n] * P.w;
                e.y = obsb[(4 + 4*q + 1)*NPIX + n] * P.w;
                e.z = obsb[(4 + 4*q + 2)*NPIX + n] * P.w;
                e.w = obsb[(4 + 4*q + 3)*NPIX + n] * P.w;
                bs[q] = e;
            }
        }
    }
}

// ---------------- pass C: per-row gather, ALL accumulation in LDS ----------
// Block = (j-row, i-half, b): 50 cells. Both streams read as 2 contiguous
// f1-segments. Occupancy: per-lane points, <=4 LDS atomics each.
// Semantics: 16 lanes per point, lane c owns channel c.
__global__ __launch_bounds__(256)
void gather_rows_kernel(const float4* __restrict__ payloadPos,
                        const int* __restrict__ offsets,
                        const float4* __restrict__ bandPos,
                        const float* __restrict__ bandSemF,
                        const int* __restrict__ offsetsB,
                        float* __restrict__ avwin,
                        float* __restrict__ fp_out)
{
    int j  = blockIdx.x >> 1;
    int i0 = (blockIdx.x & 1) * 50;
    int b  = blockIdx.y;
    int tid = threadIdx.x;

    __shared__ float accSem[50*NSEMC*ZWP];   // 10400 floats (41.6 KB)
    __shared__ float accOcc[50*OCCP];        //  4050 floats (16.2 KB)

    for (int k = tid; k < 50*NSEMC*ZWP; k += 256) accSem[k] = 0.0f;
    for (int k = tid; k < 50*OCCP; k += 256) accOcc[k] = 0.0f;
    __syncthreads();

    if (j >= 1) {
        int f0lo = (i0 == 0) ? 0 : (i0 - 1);
        int f0hi = i0 + 49;                    // <= 99
        int tmin = (i0 == 0) ? 1 : i0;
        int cgrp = tid & 15;
        #pragma unroll
        for (int seg = 0; seg < 2; ++seg) {
            int f1r = j - 1 + seg;
            int rb = (b*NBINS_DIM + f1r)*NBINS_ROW;

            // ---- all-points stream: occupancy into LDS ----
            int s = offsets[rb + f0lo];
            int e = offsets[rb + f0hi + 1];
            if (s < 0) s = 0;
            if (e > NTOT) e = NTOT;
            for (int idx = s + tid; idx < e; idx += 256) {
                float4 P = payloadPos[idx];
                float wy = 1.0f - fabsf(P.y - (float)j);
                if (wy <= 0.0f) continue;
                int f0c = (int)floorf(P.x);
                int qA  = (int)floorf(P.z);
                #pragma unroll
                for (int di = 0; di < 2; ++di) {
                    int ti = f0c + di;
                    if (ti < tmin || ti > i0 + 49) continue;
                    float wx = 1.0f - fabsf(P.x - (float)ti);
                    if (wx <= 0.0f) continue;
                    float wxy = wx * wy;
                    int base = (ti - i0)*OCCP;
                    #pragma unroll
                    for (int dz = 0; dz < 2; ++dz) {
                        int q = qA + dz;
                        if (q < 1 || q > 79) continue;
                        float w = wxy * (1.0f - fabsf(P.z - (float)q));
                        if (w > 0.0f) atomicAdd(&accOcc[base + q], P.w * w);
                    }
                }
            }

            // ---- band stream: semantics into LDS (16 lanes/point) ----
            int sB = offsetsB[rb + f0lo];
            int eB = offsetsB[rb + f0hi + 1];
            if (sB < 0) sB = 0;
            if (eB > BANDMAX) eB = BANDMAX;
            for (int idx = sB + (tid >> 4); idx < eB; idx += 16) {
                float4 P = bandPos[idx];
                float wy = 1.0f - fabsf(P.y - (float)j);
                if (wy <= 0.0f) continue;
                float ev = bandSemF[(size_t)idx*16 + cgrp];
                int f0c = (int)floorf(P.x);
                int qA  = (int)floorf(P.z);
                #pragma unroll
                for (int di = 0; di < 2; ++di) {
                    int ti = f0c + di;
                    if (ti < tmin || ti > i0 + 49) continue;
                    float wx = 1.0f - fabsf(P.x - (float)ti);
                    if (wx <= 0.0f) continue;
                    float wxy = wx * wy;
                    int base = ((ti - i0)*NSEMC + cgrp)*ZWP - MINZc;
                    #pragma unroll
                    for (int dz = 0; dz < 2; ++dz) {
                        int q = qA + dz;
                        if (q < MINZc || q >= MAXZc) continue;
                        float w = wxy * (1.0f - fabsf(P.z - (float)q));
                        if (w > 0.0f) atomicAdd(&accSem[base + q], ev * w);
                    }
                }
            }
        }
    }
    __syncthreads();

    float* avb = avwin + (size_t)b*18*10000;
    int cell0 = j*100 + i0;

    for (int c = tid; c < 50; c += 256) {
        float agent = 0.0f, all = 0.0f;
        for (int z = 0; z < HZc; ++z) {
            float r = rintf(accOcc[c*OCCP + z]);
            all += r;
            if (z >= MINZc && z < MAXZc) agent += r;
        }
        float va = fminf(fmaxf(agent, 0.0f), 1.0f);
        avb[cell0 + c] = va;
        fp_out[(size_t)b*10000 + cell0 + c] = va;
        avb[10000 + cell0 + c] = fminf(fmaxf(all, 0.0f), 1.0f);
    }
    for (int t = tid; t < 50*NSEMC; t += 256) {
        int c = t >> 4, ch = t & 15;
        float s = 0.0f;
        #pragma unroll
        for (int z = 0; z < ZW; ++z) s += rintf(accSem[(c*NSEMC + ch)*ZWP + z]);
        avb[(2+ch)*10000 + cell0 + c] = fminf(fmaxf(s*0.2f, 0.0f), 1.0f);
    }
}

// ---------------- fused double grid_sample + max ----------------
__device__ __forceinline__ float grid1d(int i) {
    return (float)(-1.0 + (double)i * (2.0/479.0));
}

__global__ void map_kernel(const float* __restrict__ maps_last,
                           const float* __restrict__ avwin,
                           const float* __restrict__ params,
                           float* __restrict__ map_out)
{
    int t = blockIdx.x*blockDim.x + threadIdx.x;
    if (t >= NB*MAPC*MAPC) return;
    int w = t % MAPC;
    int h = (t / MAPC) % MAPC;
    int b = t / (MAPC*MAPC);
    float ct = params[b*4+0], st = params[b*4+1];
    float sx = params[b*4+2], sy = params[b*4+3];

    float xg = grid1d(w) + sx;
    float yg = grid1d(h) + sy;
    float xt = ((xg + 1.0f)*479.0f)/2.0f;
    float yt = ((yg + 1.0f)*479.0f)/2.0f;
    float xf = floorf(xt), yf = floorf(yt);

    float acc[18];
    #pragma unroll
    for (int k=0;k<18;k++) acc[k]=0.0f;
    const float* avb = avwin + (size_t)b*18*10000;

    #pragma unroll
    for (int oy=0; oy<2; ++oy) {
        #pragma unroll
        for (int ox=0; ox<2; ++ox) {
            float qx = xf + (float)ox, qy = yf + (float)oy;
            if (!(qx >= 0.0f && qx < 480.0f && qy >= 0.0f && qy < 480.0f)) continue;
            float wo = (ox ? (xt - xf) : (xf + 1.0f - xt))
                     * (oy ? (yt - yf) : (yf + 1.0f - yt));
            int oxi = (int)qx, oyi = (int)qy;
            float gxr = grid1d(oxi), gyr = grid1d(oyi);
            float xr = ct*gxr - st*gyr;
            float yr = st*gxr + ct*gyr;
            float xp = ((xr + 1.0f)*479.0f)/2.0f;
            float yp = ((yr + 1.0f)*479.0f)/2.0f;
            float xpf = floorf(xp), ypf = floorf(yp);
            float R[18];
            #pragma unroll
            for (int k=0;k<18;k++) R[k]=0.0f;
            #pragma unroll
            for (int iy=0; iy<2; ++iy) {
                #pragma unroll
                for (int ix=0; ix<2; ++ix) {
                    float rx = xpf + (float)ix, ry = ypf + (float)iy;
                    if (!(rx >= 0.0f && rx < 480.0f && ry >= 0.0f && ry < 480.0f)) continue;
                    int rxi = (int)rx, ryi = (int)ry;
                    if (ryi < 240 || ryi >= 340 || rxi < 190 || rxi >= 290) continue;
                    float wi = (ix ? (xp - xpf) : (xpf + 1.0f - xp))
                             * (iy ? (yp - ypf) : (ypf + 1.0f - yp));
                    const float* p = avb + (ryi-240)*VRc + (rxi-190);
                    #pragma unroll
                    for (int k=0;k<18;k++) R[k] += wi * p[k*10000];
                }
            }
            #pragma unroll
            for (int k=0;k<18;k++) acc[k] += wo * R[k];
        }
    }

    #pragma unroll
    for (int c=0;c<COBS;c++) {
        size_t o = (((size_t)b*COBS + c)*MAPC + h)*MAPC + w;
        float tv = (c==0) ? acc[0] : (c==1) ? acc[1] : (c>=4) ? acc[c-2] : 0.0f;
        map_out[o] = fmaxf(maps_last[o], tv);
    }
}

extern "C" void kernel_launch(void* const* d_in, const int* in_sizes, int n_in,
                              void* d_out, int out_size, void* d_ws, size_t ws_size,
                              hipStream_t stream)
{
    const float* obs        = (const float*)d_in[0];
    const float* pose_obs   = (const float*)d_in[1];
    const float* maps_last  = (const float*)d_in[2];
    const float* poses_last = (const float*)d_in[3];
    const float* sh         = (const float*)d_in[4];
    float* out = (float*)d_out;

    float* fp_out  = out;                       // 40,000
    float* map_out = out + 40000;               // 18,432,000
    float* poses1  = out + 40000 + 18432000;    // 12
    float* poses2  = poses1 + 12;               // 12

    float* params = (float*)d_ws;               // 16 floats
    float* avwin  = params + 16;                // 720,000 floats

    // Scratch inside map_out region (fully overwritten by final map_kernel):
    //  payloadPos : NTOT*4 = 4,915,200 floats
    //  counts x4  : 4*40,960 ints = 163,840 floats
    //  bandPos    : BANDMAX*4  = 2,400,000 floats
    //  bandSem    : BANDMAX*16 = 9,600,000 floats
    //  total = 17,079,040 floats <= 18,432,000
    float4* payloadPos   = (float4*)map_out;
    int*    counts       = (int*)(map_out + 4915200);
    int*    offsetsWork  = counts + COUNTS_PAD;
    int*    countsB      = counts + 2*COUNTS_PAD;
    int*    offsetsWorkB = counts + 3*COUNTS_PAD;
    float4* bandPos      = (float4*)(map_out + 4915200 + 4*COUNTS_PAD);
    float4* bandSem      = (float4*)(map_out + 4915200 + 4*COUNTS_PAD + (size_t)BANDMAX*4);

    double rad = 39.5 * 0.017453292519943295;
    float fconst = (float)(320.0 / tan(rad));

    hipLaunchKernelGGL(pose_kernel, dim3(1), dim3(64), 0, stream,
                       pose_obs, poses_last, poses1, poses2, params);

    hipMemsetAsync(counts, 0, (size_t)4*COUNTS_PAD*sizeof(int), stream);

    hipLaunchKernelGGL(count_kernel, dim3((NTOT+255)/256), dim3(256), 0, stream,
                       obs, sh, counts, countsB, fconst);

    hipLaunchKernelGGL(scan_kernel, dim3(2), dim3(1024), 0, stream, counts);

    hipLaunchKernelGGL(scatter_kernel, dim3((NTOT+255)/256), dim3(256), 0, stream,
                       obs, sh, offsetsWork, offsetsWorkB,
                       payloadPos, bandPos, bandSem, fconst);

    hipLaunchKernelGGL(gather_rows_kernel, dim3(200, NB), dim3(256), 0, stream,
                       payloadPos, counts, bandPos, (const float*)bandSem, countsB,
                       avwin, fp_out);

    hipLaunchKernelGGL(map_kernel, dim3((NB*MAPC*MAPC+255)/256), dim3(256), 0, stream,
                       maps_last, avwin, params, map_out);
}